// Round 9
// baseline (195.992 us; speedup 1.0000x reference)
//
#include <hip/hip_runtime.h>
#include <math.h>

// ---------------- problem constants ----------------
#define GAMMA_ 0.01f
#define WARP_  134.4f
#define INFV   100000.0f
#define BIGV   1000000000.0f

#define B_  4
#define H_  192
#define TP_ 350
#define TQ_ 400

// ---------------- workspace layout (float offsets) ----------------
// acc[0]=gen acc[1]=e2e acc[2]=fm acc[3]=mel acc[4]=dur acc[5]=sum_pm acc[6]=sum_qm
#define ACC_OFF 0
#define DTW_OFF 16                          // 8 results: [which*4 + b]
#define SLP_OFF 32                          // sum_h logs_p  [B][350]
#define SLQ_OFF (SLP_OFF + B_*TP_)          // sum_h logs_q  [B][400]
// D-matrices with masks BAKED IN (incl. pad row/col), transposed [J][I]:
#define KL1_OFF 3072
#define KL1_NCOL 401
#define KL1_PITCHT 352
#define KL2_OFF (KL1_OFF + B_*KL1_NCOL*KL1_PITCHT)
#define KL2_NCOL 351
#define KL2_PITCHT 408

// LDS ring: 43 column slots x 416 bf16 (832 B each) = 35,776 B.
// Live window with RB=16 (lres<=25): [t0-25, t0+15] = 41 cols < 43 -> no alias.
#define RING_SLOTS 43
#define RING_PITCH 416

typedef float f4_t __attribute__((ext_vector_type(4)));

__device__ __forceinline__ unsigned pk2(float a, float b) {
    unsigned ua = __float_as_uint(a), ub = __float_as_uint(b);
    ua = (ua + 0x7FFFu + ((ua >> 16) & 1u)) >> 16;          // RTN bf16 of a (low half)
    ub = (ub + 0x7FFFu + ((ub >> 16) & 1u)) & 0xFFFF0000u;  // RTN bf16 of b (high half)
    return ua | ub;
}
__device__ __forceinline__ int mod43(int x) { return x - (x / RING_SLOTS) * RING_SLOTS; }

// per-position sums over h of logs_p / logs_q  (+ zero the accumulators)
__global__ void sl_kernel(const float* __restrict__ logs_p,
                          const float* __restrict__ logs_q,
                          float* __restrict__ ws) {
    int t = blockIdx.x * 256 + threadIdx.x;
    if (t < 32) ws[ACC_OFF + t] = 0.f;
    if (t < B_ * TP_) {
        int b = t / TP_, i = t % TP_;
        const float* p = logs_p + (size_t)b * H_ * TP_ + i;
        float s = 0.f;
        for (int h = 0; h < H_; ++h) s += p[(size_t)h * TP_];
        ws[SLP_OFF + t] = s;
    } else if (t < B_ * TP_ + B_ * TQ_) {
        int t2 = t - B_ * TP_;
        int b = t2 / TQ_, j = t2 % TQ_;
        const float* p = logs_q + (size_t)b * H_ * TQ_ + j;
        float s = 0.f;
        for (int h = 0; h < H_; ++h) s += p[(size_t)h * TQ_];
        ws[SLQ_OFF + t2] = s;
    }
}

// Writes the fully-masked D matrix (transposed, [J][I]) including pad row I=R and
// pad col J=C:  D = (pb&&qb) ? kl : (pb^qb ? INF : 0),  pb/qb false on pads.
__global__ void kl_kernel(const float* __restrict__ mp, const float* __restrict__ lsp,
                          const float* __restrict__ zp,
                          const float* __restrict__ mq, const float* __restrict__ lsq,
                          const float* __restrict__ zq,
                          const float* __restrict__ pmask, const float* __restrict__ zmask,
                          float* __restrict__ ws) {
    int which = blockIdx.z >> 2;
    int b     = blockIdx.z & 3;
    const float *mS, *lS, *zS, *SLrow, *SLcol, *rm, *cm; float* out; int R, C, pitchT;
    if (which == 0) { mS=mp; lS=lsp; zS=zp; SLrow=ws+SLP_OFF; SLcol=ws+SLQ_OFF;
                      rm=pmask + b*TP_; cm=zmask + b*TQ_;
                      out=ws+KL1_OFF + (size_t)b*KL1_NCOL*KL1_PITCHT;
                      R=TP_; C=TQ_; pitchT=KL1_PITCHT; }
    else            { mS=mq; lS=lsq; zS=zq; SLrow=ws+SLQ_OFF; SLcol=ws+SLP_OFF;
                      rm=zmask + b*TQ_; cm=pmask + b*TP_;
                      out=ws+KL2_OFF + (size_t)b*KL2_NCOL*KL2_PITCHT;
                      R=TQ_; C=TP_; pitchT=KL2_PITCHT; }
    int i0 = blockIdx.x * 32;
    int j0 = blockIdx.y * 32;
    if (i0 > R || j0 > C) return;
    __shared__ __align__(16) float wS [16][32];
    __shared__ __align__(16) float mSh[16][32];
    __shared__ __align__(16) float zSh[16][32];
    const float* mB = mS + (size_t)b * H_ * R;
    const float* lB = lS + (size_t)b * H_ * R;
    const float* zB = zS + (size_t)b * H_ * C;
    int tx = threadIdx.x, ty = threadIdx.y;
    int t  = ty * 16 + tx;
    float a00 = 0.f, a01 = 0.f, a10 = 0.f, a11 = 0.f;
    for (int h0 = 0; h0 < H_; h0 += 16) {
        for (int e = t; e < 512; e += 256) {
            int hh = e >> 5, cc = e & 31;
            int h = h0 + hh;
            int gi = i0 + cc, gj = j0 + cc;
            float wv = 0.f, mv = 0.f;
            if (gi < R) {
                wv = __expf(-2.f * lB[(size_t)h * R + gi]);
                mv = mB[(size_t)h * R + gi];
            }
            wS[hh][cc] = wv; mSh[hh][cc] = mv;
            zSh[hh][cc] = (gj < C) ? zB[(size_t)h * C + gj] : 0.f;
        }
        __syncthreads();
#pragma unroll
        for (int kk = 0; kk < 16; ++kk) {
            float2 wv = *(const float2*)&wS [kk][tx * 2];
            float2 mv = *(const float2*)&mSh[kk][tx * 2];
            float2 zv = *(const float2*)&zSh[kk][ty * 2];
            float d;
            d = zv.x - mv.x; a00 += wv.x * d * d;
            d = zv.x - mv.y; a01 += wv.y * d * d;
            d = zv.y - mv.x; a10 += wv.x * d * d;
            d = zv.y - mv.y; a11 += wv.y * d * d;
        }
        __syncthreads();
    }
    float accs[2][2] = {{a00, a01}, {a10, a11}};
    for (int jj = 0; jj < 2; ++jj)
        for (int ii = 0; ii < 2; ++ii) {
            int I = i0 + tx * 2 + ii, J = j0 + ty * 2 + jj;
            if (I <= R && J <= C) {
                bool pbI = (I < R) && (rm[I] != 0.f);
                bool qbJ = (J < C) && (cm[J] != 0.f);
                float v;
                if (pbI & qbJ)
                    v = SLrow[b * R + I] - SLcol[b * C + J] - 0.5f * H_ + 0.5f * accs[jj][ii];
                else
                    v = (pbI ^ qbJ) ? INFV : 0.f;
                out[(size_t)J * pitchT + I] = v;
            }
        }
}

// stager macros: load chunk q (8 cols) element (cc,ii) from klT; store to ring (bf16)
#define SLD(q, r, cc, ii, vv) { int col_ = ((q) << 3) + (cc); \
    if ((vv) && col_ <= C_) r = *(const f4_t*)(klT + (size_t)col_ * pitchT + ((ii) << 2)); }
#define SST(q, r, cc, ii, vv) { int col_ = ((q) << 3) + (cc); \
    if ((vv) && col_ <= C_) { int s_ = mod43(col_); \
        uint2 u_; u_.x = pk2(r.x, r.y); u_.y = pk2(r.z, r.w); \
        *(uint2*)&ring[s_][(ii) << 2] = u_; } }

#define UNPK(da, db, src) \
    float da = __uint_as_float((unsigned)(src) << 16); \
    float db = __uint_as_float((unsigned)(src) & 0xFFFF0000u);
#define PRE(k, km1) float q##k = fminf(p##km1 + d##k, p##k + (WARP_ + d##k));
#define CH(k) u_ = fminf(q##k, u_ + (WARP_ + d##k)); p##k = u_;

// Fused: blocks 0..7 = soft-DTW producer/consumer LDS ring (RB=16, 26 active lanes);
//        blocks 8..  = grid-stride streaming reductions (feats unroll x2).
__global__ __launch_bounds__(512, 4) void main_kernel(
    const float* __restrict__ mel, const float* __restrict__ melh,
    const float* __restrict__ sg,  const float* __restrict__ se,
    const float* __restrict__ fr,  const float* __restrict__ ff,
    const float* __restrict__ dur, float* ws) {
    __shared__ __align__(16) unsigned short ring[RING_SLOTS][RING_PITCH];
    int bid = blockIdx.x, tid = threadIdx.x;
    if (bid < 8) {
        int b = bid & 3, which = bid >> 2;
        int R_, C_, pitchT;
        const float* klT;
        if (which == 0) {
            R_ = TP_; C_ = TQ_; pitchT = KL1_PITCHT;
            klT = ws + KL1_OFF + (size_t)b * KL1_NCOL * KL1_PITCHT;
        } else {
            R_ = TQ_; C_ = TP_; pitchT = KL2_PITCHT;
            klT = ws + KL2_OFF + (size_t)b * KL2_NCOL * KL2_PITCHT;
        }
        int lres = R_ >> 4;                   // 21 (kl1) / 25 (kl2)
        int tmax = C_ + lres;                 // 421 / 375
        int P = (tmax >> 3) + 1;              // 53 / 47 phases of 8 steps

        if (tid < 64) {
            // ---------------- consumer wave (lanes 0..lres active) ----------------
            int lane = tid; bool lane0 = (lane == 0);
            int lnOff = (lane < 26 ? lane : 25) << 4;   // bf16 offset within slot
            float p0=BIGV,p1=BIGV,p2=BIGV,p3=BIGV,p4=BIGV,p5=BIGV,p6=BIGV,p7=BIGV,
                  p8=BIGV,p9=BIGV,p10=BIGV,p11=BIGV,p12=BIGV,p13=BIGV,p14=BIGV,p15=BIGV;
            float recv_cur = BIGV, recv_prev = BIGV;
            __syncthreads();                  // B0: chunk 0 staged
            for (int ph = 0; ph < P; ++ph) {
                int t0 = ph << 3;
                int c0 = t0 - lane;
                int cr = c0 < 0 ? 0 : (c0 > C_ ? C_ : c0);
                int s0 = mod43(cr);
                int4 n0 = *(const int4*)&ring[s0][lnOff];
                int4 n1 = *(const int4*)&ring[s0][lnOff + 8];
#pragma unroll
                for (int i = 0; i < 8; ++i) {
                    int c = t0 + i - lane;
                    int4 r0 = n0, r1 = n1;
                    if (i < 7) {              // prefetch next column (within staged chunks)
                        int cn = c + 1; cn = cn < 0 ? 0 : (cn > C_ ? C_ : cn);
                        int sn = mod43(cn);
                        n0 = *(const int4*)&ring[sn][lnOff];
                        n1 = *(const int4*)&ring[sn][lnOff + 8];
                    }
                    float last_ = 0.f;
                    if ((unsigned)c <= (unsigned)C_) {
                        float u_  = lane0 ? BIGV : recv_cur;
                        float dg  = (c == 0) ? (lane0 ? 0.f : BIGV) : (lane0 ? BIGV : recv_prev);
                        UNPK(d0,  d1,  r0.x) UNPK(d2,  d3,  r0.y)
                        UNPK(d4,  d5,  r0.z) UNPK(d6,  d7,  r0.w)
                        UNPK(d8,  d9,  r1.x) UNPK(d10, d11, r1.y)
                        UNPK(d12, d13, r1.z) UNPK(d14, d15, r1.w)
                        float q0 = fminf(dg + d0, p0 + (WARP_ + d0));
                        PRE(1,0)  PRE(2,1)   PRE(3,2)   PRE(4,3)
                        PRE(5,4)  PRE(6,5)   PRE(7,6)   PRE(8,7)
                        PRE(9,8)  PRE(10,9)  PRE(11,10) PRE(12,11)
                        PRE(13,12) PRE(14,13) PRE(15,14)
                        CH(0) CH(1) CH(2) CH(3) CH(4) CH(5) CH(6) CH(7)
                        CH(8) CH(9) CH(10) CH(11) CH(12) CH(13) CH(14) CH(15)
                        last_ = u_;
                    }
                    recv_prev = recv_cur;
                    recv_cur  = __shfl_up(last_, 1);
                }
                __syncthreads();              // chunk ph+1 writes complete
            }
            float r14 = __shfl(p14, lres);    // kl1 answer: lane 21, k=14
            float r0x = __shfl(p0,  lres);    // kl2 answer: lane 25, k=0
            if (lane0) ws[DTW_OFF + which * 4 + b] = (which == 0) ? r14 : r0x;
        } else {
            // ---------------- stager waves (1..7) ----------------
            int st  = tid - 64;               // 0..447
            int n4  = pitchT >> 2;            // 88 / 102 float4s per column
            int tot = n4 << 3;                // per-chunk elements (704 / 816)
            int cA = st / n4,  iA = st - cA * n4;
            int eB = st + 448; int cB = eB / n4, iB = eB - cB * n4;
            bool vA = st < tot, vB = eB < tot;
            f4_t rA = {0.f,0.f,0.f,0.f}, rB = {0.f,0.f,0.f,0.f};
            SLD(0, rA, cA, iA, vA) SLD(0, rB, cB, iB, vB)
            SST(0, rA, cA, iA, vA) SST(0, rB, cB, iB, vB)
            SLD(1, rA, cA, iA, vA) SLD(1, rB, cB, iB, vB)
            __syncthreads();                  // B0
            for (int p = 0; p < P; ++p) {
                SST(p + 1, rA, cA, iA, vA) SST(p + 1, rB, cB, iB, vB)
                SLD(p + 2, rA, cA, iA, vA) SLD(p + 2, rB, cB, iB, vB)
                __syncthreads();
            }
        }
    } else {
        // ---------------- reductions ----------------
        int rid = bid - 8;
        long T = (long)(gridDim.x - 8) * 512;
        long gid = (long)rid * 512 + tid;
        const float4* fr4   = (const float4*)fr;
        const float4* ff4   = (const float4*)ff;
        const float4* sg4   = (const float4*)sg;
        const float4* se4   = (const float4*)se;
        const float4* mel4  = (const float4*)mel;
        const float4* melh4 = (const float4*)melh;
        const float4* dur4  = (const float4*)dur;
        const long E0 = 12582912;             // feats float4s (97% of bytes)
        float a2 = 0.f;
        long v = gid;
        for (; v + T < E0; v += 2 * T) {      // 4 independent 16B loads in flight
            float4 x0 = fr4[v],     y0 = ff4[v];
            float4 x1 = fr4[v + T], y1 = ff4[v + T];
            a2 += fabsf(x0.x-y0.x)+fabsf(x0.y-y0.y)+fabsf(x0.z-y0.z)+fabsf(x0.w-y0.w);
            a2 += fabsf(x1.x-y1.x)+fabsf(x1.y-y1.y)+fabsf(x1.z-y1.z)+fabsf(x1.w-y1.w);
        }
        for (; v < E0; v += T) {
            float4 x = fr4[v], y = ff4[v];
            a2 += fabsf(x.x-y.x)+fabsf(x.y-y.y)+fabsf(x.z-y.z)+fabsf(x.w-y.w);
        }
        float a0=0.f, a1=0.f, a3=0.f, a4=0.f;
        long w = gid;                         // tail: 108,894 float4s, <=1 per thread
        if (w < 108894) {
            if (w < 49152) {
                float4 s = sg4[w]; float e;
                e=1.f-s.x; a0+=e*e; e=1.f-s.y; a0+=e*e; e=1.f-s.z; a0+=e*e; e=1.f-s.w; a0+=e*e;
            } else if (w < 98304) {
                float4 s = se4[w - 49152]; float e;
                e=1.f-s.x; a1+=e*e; e=1.f-s.y; a1+=e*e; e=1.f-s.z; a1+=e*e; e=1.f-s.w; a1+=e*e;
            } else if (w < 108544) {
                float4 x = mel4[w - 98304], y = melh4[w - 98304];
                a3 += fabsf(x.x-y.x)+fabsf(x.y-y.y)+fabsf(x.z-y.z)+fabsf(x.w-y.w);
            } else {
                float4 x = dur4[w - 108544]; a4 += x.x + x.y + x.z + x.w;
            }
        }
        float vals[5] = {a0, a1, a2, a3, a4};
        float* sb = (float*)ring;             // reduction blocks never touch the ring
#pragma unroll
        for (int q = 0; q < 5; ++q) {
            float x = vals[q];
            for (int off = 32; off > 0; off >>= 1) x += __shfl_xor(x, off);
            if ((tid & 63) == 0) sb[(tid >> 6) * 8 + q] = x;
        }
        __syncthreads();
        if (tid < 5) {
            float s = 0.f;
            for (int w2 = 0; w2 < 8; ++w2) s += sb[w2 * 8 + tid];
            atomicAdd(&ws[ACC_OFF + tid], s);
        }
    }
}

// mask sums (tiny): acc[5] = sum(pmask), acc[6] = sum(zmask)
__global__ void masksum_kernel(const float* __restrict__ pmask,
                               const float* __restrict__ zmask,
                               float* __restrict__ ws) {
    int tid = threadIdx.x;   // 256 threads, 1 block
    float a5 = 0.f, a6 = 0.f;
    for (int v = tid; v < B_ * TP_; v += 256) a5 += pmask[v];
    for (int v = tid; v < B_ * TQ_; v += 256) a6 += zmask[v];
    __shared__ float s5[4], s6[4];
    for (int off = 32; off > 0; off >>= 1) { a5 += __shfl_xor(a5, off); a6 += __shfl_xor(a6, off); }
    if ((tid & 63) == 0) { s5[tid >> 6] = a5; s6[tid >> 6] = a6; }
    __syncthreads();
    if (tid == 0) {
        ws[5] = s5[0] + s5[1] + s5[2] + s5[3];
        ws[6] = s6[0] + s6[1] + s6[2] + s6[3];
    }
}

__global__ void final_kernel(const float* __restrict__ ws,
                             const float* __restrict__ ldl,
                             float* __restrict__ out) {
    if (threadIdx.x == 0 && blockIdx.x == 0) {
        float gen  = ws[0] * (1.f / 32768.f);
        float e2e  = ws[1] * (1.f / 32768.f);
        float fm   = ws[2] * (2.f / 2097152.f);
        float melv = ws[3] * (45.f / 40960.f);
        float durv = ws[4];
        float dlen = logf(ldl[0] + 1e-6f);
        float kl  = (ws[DTW_OFF + 0] + ws[DTW_OFF + 1] + ws[DTW_OFF + 2] + ws[DTW_OFF + 3]) / ws[5];
        float klf = (ws[DTW_OFF + 4] + ws[DTW_OFF + 5] + ws[DTW_OFF + 6] + ws[DTW_OFF + 7]) / ws[6];
        out[0] = gen + e2e + fm + melv + durv + dlen + kl + klf;
    }
}

extern "C" void kernel_launch(void* const* d_in, const int* in_sizes, int n_in,
                              void* d_out, int out_size, void* d_ws, size_t ws_size,
                              hipStream_t stream) {
    const float* mel    = (const float*)d_in[0];
    const float* melh   = (const float*)d_in[1];
    const float* sg     = (const float*)d_in[2];
    const float* se     = (const float*)d_in[3];
    const float* fr     = (const float*)d_in[4];
    const float* ff     = (const float*)d_in[5];
    const float* dur    = (const float*)d_in[6];
    const float* ldl    = (const float*)d_in[7];
    // d_in[8] = loss_pitch (unused by reference)
    const float* z_p    = (const float*)d_in[9];
    const float* m_p    = (const float*)d_in[10];
    const float* logs_p = (const float*)d_in[11];
    const float* z_q    = (const float*)d_in[12];
    const float* m_q    = (const float*)d_in[13];
    const float* logs_q = (const float*)d_in[14];
    const float* pmask  = (const float*)d_in[15];
    const float* zmask  = (const float*)d_in[16];  // (B,1,TQ) == flat (B,TQ)
    float* ws  = (float*)d_ws;
    float* out = (float*)d_out;

    sl_kernel<<<12, 256, 0, stream>>>(logs_p, logs_q, ws);
    masksum_kernel<<<1, 256, 0, stream>>>(pmask, zmask, ws);
    kl_kernel<<<dim3(13, 13, 8), dim3(16, 16), 0, stream>>>(
        m_p, logs_p, z_p, m_q, logs_q, z_q, pmask, zmask, ws);
    main_kernel<<<8 + 1016, 512, 0, stream>>>(mel, melh, sg, se, fr, ff, dur, ws);
    final_kernel<<<1, 64, 0, stream>>>(ws, ldl, out);
}